// Round 8
// baseline (808.807 us; speedup 1.0000x reference)
//
#include <hip/hip_runtime.h>

#define KK 27
#define NBLK 1024   // 4 blocks/CU x 256 CUs; residency forced by __launch_bounds__(256,4)
                    // (VGPR<=128 -> 4 waves/SIMD) + LDS 16.9KB (<160/4 KB). Grid-stride
                    // loops keep the kernel correct for any grid size regardless.

typedef short bf16x8 __attribute__((ext_vector_type(8)));   // 8 bf16 in 4 VGPRs
typedef float f32x4  __attribute__((ext_vector_type(4)));

__device__ inline unsigned short f2bf(float f) {            // RNE fp32 -> bf16
    unsigned u = __float_as_uint(f);
    unsigned r = u + 0x7fffu + ((u >> 16) & 1u);
    return (unsigned short)(r >> 16);
}

// One-shot grid barrier (each instance used once per kernel execution; state zeroed
// by hipMemsetAsync before launch, re-zeroed on every graph replay).
// Cross-XCD safety: __threadfence() = agent-scope fence (L2 wb/inv) on both sides;
// counter/flag are agent-scope atomics. Spin only in thread 0, with s_sleep.
__device__ __forceinline__ void grid_barrier(int* cnt, int* flag) {
    __threadfence();                               // release this block's writes
    __syncthreads();
    if (threadIdx.x == 0) {
        if (__hip_atomic_fetch_add(cnt, 1, __ATOMIC_ACQ_REL, __HIP_MEMORY_SCOPE_AGENT)
            == (int)gridDim.x - 1) {
            __hip_atomic_store(flag, 1, __ATOMIC_RELEASE, __HIP_MEMORY_SCOPE_AGENT);
        } else {
            while (__hip_atomic_load(flag, __ATOMIC_ACQUIRE, __HIP_MEMORY_SCOPE_AGENT) == 0)
                __builtin_amdgcn_s_sleep(8);
        }
    }
    __syncthreads();
    __threadfence();                               // acquire for every thread
}

// Single regular-launch kernel: prep -> barrier -> conv -> barrier -> stats+norm.
// Eliminates the ~80-90us inter-dispatch residue (3 launches -> 1) and makes all
// 3125 conv waves resident from t=0 (16 waves/CU vs 7.4 measured in the 3-launch
// pipeline) for the latency-bound random-gather phase.
__global__ __launch_bounds__(256, 4) void fused_k(const float* __restrict__ in,
                                                  const int* __restrict__ neigh,
                                                  const float* __restrict__ w,
                                                  const float* __restrict__ gamma,
                                                  const float* __restrict__ beta,
                                                  float* __restrict__ y,     // out [32][N]
                                                  unsigned short* __restrict__ xTb,
                                                  unsigned short* __restrict__ wTb,
                                                  float* __restrict__ tot,   // [32][64] striped
                                                  int* __restrict__ bar,     // 4 ints, pre-zeroed
                                                  int N) {
    __shared__ float lds[4 * 32 * 33];   // reused: prep tile / conv ct[4] / stats sums

    const int tid   = threadIdx.x;
    const int nxblk = (N + 31) / 32;

    // ===== Phase P: prep (grid-stride over nxblk x-tiles + KK weight taps) =====
    {
        float (*tile)[33] = reinterpret_cast<float(*)[33]>(lds);
        for (int b = blockIdx.x; b < nxblk + KK; b += (int)gridDim.x) {
            if (b < nxblk) {
                int n0 = b * 32;
                int tx = tid & 31;
                int ty = tid >> 5;  // 0..7
                __syncthreads();    // protect tile across grid-stride iterations
#pragma unroll
                for (int c = ty; c < 32; c += 8) {
                    int n = n0 + tx;
                    tile[c][tx] = (n < N) ? in[(long)c * N + n] : 0.f;
                }
                __syncthreads();
#pragma unroll
                for (int nn = ty; nn < 32; nn += 8) {
                    int n = n0 + nn;
                    if (n < N) xTb[(long)n * 32 + tx] = f2bf(tile[tx][nn]);
                }
                if (b == 0 && tid < 32) xTb[(long)N * 32 + tid] = 0;  // zero row
            } else {
                int k = b - nxblk;
                for (int i = tid; i < 1024; i += 256) {
                    int cin = i >> 5, cout = i & 31;
                    wTb[k * 1024 + cout * 32 + cin] = f2bf(w[k * 1024 + cin * 32 + cout]);
                }
                if (k == 0) {
                    for (int i = tid; i < 32 * 64; i += 256) tot[i] = 0.f;
                }
            }
        }
    }
    grid_barrier(bar + 0, bar + 1);

    // ===== Phase C: conv (R0 inner loop; one wave per 32-node tile) =====
    {
        float (*ct)[32][33] = reinterpret_cast<float(*)[32][33]>(lds);
        const int L    = tid & 63;
        const int wv   = tid >> 6;                 // 0..3 independent waves
        const int ntiles = (N + 31) / 32;
        for (int tile_id = blockIdx.x * 4 + wv; tile_id < ntiles;
             tile_id += (int)gridDim.x * 4) {
            const int r16  = L & 15;
            const int quad = L >> 4;
            const int base = tile_id * 32;
            const int n0 = base + r16;
            const int n1 = base + 16 + r16;
            const bool v0 = (n0 < N), v1 = (n1 < N);
            const long nb0 = (long)(v0 ? n0 : 0) * KK;
            const long nb1 = (long)(v1 ? n1 : 0) * KK;

            f32x4 acc00 = {0.f, 0.f, 0.f, 0.f};
            f32x4 acc01 = acc00, acc10 = acc00, acc11 = acc00;

            int ia = v0 ? neigh[nb0] : N;
            int ib = v1 ? neigh[nb1] : N;
            int ja = v0 ? neigh[nb0 + 1] : N;
            int jb = v1 ? neigh[nb1 + 1] : N;

            bf16x8 a0 = *(const bf16x8*)(xTb + (long)ia * 32 + quad * 8);
            bf16x8 a1 = *(const bf16x8*)(xTb + (long)ib * 32 + quad * 8);
            bf16x8 b0 = *(const bf16x8*)(wTb + r16 * 32 + quad * 8);
            bf16x8 b1 = *(const bf16x8*)(wTb + (16 + r16) * 32 + quad * 8);

#pragma unroll 1
            for (int k = 0; k < KK; ++k) {
                bf16x8 na0, na1, pb0, pb1;
                if (k < KK - 1) {
                    na0 = *(const bf16x8*)(xTb + (long)ja * 32 + quad * 8);
                    na1 = *(const bf16x8*)(xTb + (long)jb * 32 + quad * 8);
                    const unsigned short* wn = wTb + (k + 1) * 1024;
                    pb0 = *(const bf16x8*)(wn + r16 * 32 + quad * 8);
                    pb1 = *(const bf16x8*)(wn + (16 + r16) * 32 + quad * 8);
                    int kk = (k + 2 < KK) ? (k + 2) : (KK - 1);
                    ja = v0 ? neigh[nb0 + kk] : N;
                    jb = v1 ? neigh[nb1 + kk] : N;
                }

                acc00 = __builtin_amdgcn_mfma_f32_16x16x32_bf16(a0, b0, acc00, 0, 0, 0);
                acc01 = __builtin_amdgcn_mfma_f32_16x16x32_bf16(a0, b1, acc01, 0, 0, 0);
                acc10 = __builtin_amdgcn_mfma_f32_16x16x32_bf16(a1, b0, acc10, 0, 0, 0);
                acc11 = __builtin_amdgcn_mfma_f32_16x16x32_bf16(a1, b1, acc11, 0, 0, 0);

                if (k < KK - 1) {
                    a0 = na0;
                    a1 = na1;
                    b0 = pb0;
                    b1 = pb1;
                }
            }

            // BN partials (sum over this wave's 32 nodes), striped atomics
            float s0 = 0.f, q0 = 0.f, s1 = 0.f, q1 = 0.f;
#pragma unroll
            for (int r = 0; r < 4; ++r) {
                s0 += acc00[r] + acc10[r];
                q0 += acc00[r] * acc00[r] + acc10[r] * acc10[r];
                s1 += acc01[r] + acc11[r];
                q1 += acc01[r] * acc01[r] + acc11[r] * acc11[r];
            }
#pragma unroll
            for (int off = 16; off < 64; off <<= 1) {
                s0 += __shfl_xor(s0, off, 64);
                q0 += __shfl_xor(q0, off, 64);
                s1 += __shfl_xor(s1, off, 64);
                q1 += __shfl_xor(q1, off, 64);
            }
            const int stripe = tile_id & 31;
            if (L < 16) {
                float* tb = tot + stripe * 64;
                atomicAdd(&tb[L],      s0);
                atomicAdd(&tb[L + 16], s1);
                atomicAdd(&tb[L + 32], q0);
                atomicAdd(&tb[L + 48], q1);
            }

            // per-wave LDS transpose -> coalesced y stores (wave-private slice)
#pragma unroll
            for (int r = 0; r < 4; ++r) {
                ct[wv][quad * 4 + r][r16]           = acc00[r];
                ct[wv][quad * 4 + r][16 + r16]      = acc01[r];
                ct[wv][16 + quad * 4 + r][r16]      = acc10[r];
                ct[wv][16 + quad * 4 + r][16 + r16] = acc11[r];
            }
            const int node = L & 31;
            const int half = L >> 5;
            const int gn = base + node;
            if (gn < N) {
#pragma unroll
                for (int i = 0; i < 16; ++i) {
                    const int cout = i * 2 + half;
                    y[(long)cout * N + gn] = ct[wv][node][cout];
                }
            }
        }
    }
    grid_barrier(bar + 2, bar + 3);

    // ===== Phase S: stripe-reduce BN sums into LDS (per block, 8KB L2-hot) =====
    if (tid < 64) {
        float v = 0.f;
#pragma unroll
        for (int s = 0; s < 32; ++s) v += tot[s * 64 + tid];
        lds[tid] = v;   // [0..31] = sum per cout, [32..63] = sumsq per cout
    }
    __syncthreads();

    // ===== Phase N: normalize y in place (grid-stride, d-major for coalescing) =====
    {
        const long N4 = ((long)N + 3) >> 2;
        const long items = 32 * N4;
        const float invN = 1.f / (float)N;
        for (long it = (long)blockIdx.x * 256 + tid; it < items;
             it += (long)gridDim.x * 256) {
            const int  d  = (int)(it / N4);
            const long i4 = it - (long)d * N4;
            const float mean = lds[d] * invN;
            const float var  = lds[32 + d] * invN - mean * mean;
            const float sc   = gamma[d] * rsqrtf(var + 1e-3f);
            const float sh   = beta[d] - mean * sc;
            const long base = i4 * 4;
            float* yp = y + (long)d * N + base;
            if (base + 3 < N) {
                float4 v = *(float4*)yp;
                v.x = fmaf(v.x, sc, sh);
                v.y = fmaf(v.y, sc, sh);
                v.z = fmaf(v.z, sc, sh);
                v.w = fmaf(v.w, sc, sh);
                *(float4*)yp = v;
            } else if (base < N) {
                for (long t = base; t < N; ++t)
                    y[(long)d * N + t] = fmaf(y[(long)d * N + t], sc, sh);
            }
        }
    }
}

// ---- launcher: memset barrier state + ONE regular launch (graph-capture safe) ----
extern "C" void kernel_launch(void* const* d_in, const int* in_sizes, int n_in,
                              void* d_out, int out_size, void* d_ws, size_t ws_size,
                              hipStream_t stream) {
    const float* data_in = (const float*)d_in[0];
    const int*   neigh   = (const int*)d_in[1];
    const float* weight  = (const float*)d_in[2];
    const float* gamma   = (const float*)d_in[3];
    const float* beta    = (const float*)d_in[4];
    float* out = (float*)d_out;

    int N = in_sizes[1] / KK;

    char* ws = (char*)d_ws;
    unsigned short* xTb = (unsigned short*)ws;                            // (N+1)*32 bf16
    unsigned short* wTb = (unsigned short*)(ws + (size_t)(N + 1) * 64);   // 27*1024 bf16
    float* tot = (float*)(ws + (size_t)(N + 1) * 64 + 55296);             // 32*64 floats
    int*   bar = (int*)(tot + 32 * 64);                                   // 4 ints

    hipMemsetAsync(bar, 0, 4 * sizeof(int), stream);
    fused_k<<<dim3(NBLK), dim3(256), 0, stream>>>(data_in, neigh, weight, gamma, beta,
                                                  out, xTb, wTb, tot, bar, N);
}

// Round 9
// 251.463 us; speedup vs baseline: 3.2164x; 3.2164x over previous
//
#include <hip/hip_runtime.h>

#define KK 27

typedef short bf16x8 __attribute__((ext_vector_type(8)));   // 8 bf16 in 4 VGPRs
typedef float f32x4  __attribute__((ext_vector_type(4)));

__device__ inline unsigned short f2bf(float f) {            // RNE fp32 -> bf16
    unsigned u = __float_as_uint(f);
    unsigned r = u + 0x7fffu + ((u >> 16) & 1u);
    return (unsigned short)(r >> 16);
}

// One-shot grid barrier, XCD-safe WITHOUT invalidation storms.
// R8 lesson: an agent-scope ACQUIRE load in the spin emits cache-invalidation every
// poll -> spinning blocks destroyed all XCDs' caches (786us kernel). Correct form:
// RELAXED coherence-point loads in the spin; ONE release fence before arrival and
// ONE acquire fence after the flag is seen.
__device__ __forceinline__ void grid_barrier(int* cnt, int* flag) {
    __syncthreads();                       // all block's memory ops issued & drained
    if (threadIdx.x == 0) {
        __builtin_amdgcn_fence(__ATOMIC_RELEASE, "agent");    // publish block's writes
        int arrived = __hip_atomic_fetch_add(cnt, 1, __ATOMIC_RELAXED,
                                             __HIP_MEMORY_SCOPE_AGENT);
        if (arrived == (int)gridDim.x - 1) {
            __hip_atomic_store(flag, 1, __ATOMIC_RELAXED, __HIP_MEMORY_SCOPE_AGENT);
        } else {
            while (__hip_atomic_load(flag, __ATOMIC_RELAXED,
                                     __HIP_MEMORY_SCOPE_AGENT) == 0)
                __builtin_amdgcn_s_sleep(32);                 // ~2k cy backoff, no inv
        }
        __builtin_amdgcn_fence(__ATOMIC_ACQUIRE, "agent");    // single L1/L2 inv
    }
    __syncthreads();
}

// Single regular-launch kernel: prep -> barrier -> conv -> barrier -> stats+norm.
// Grid sized to exactly the conv need (ceil(ntiles/4) blocks, ~782 for N=100k) so
// no block is structurally idle at the second barrier. Co-residency: 782 <= 1024
// slots (4 blocks/CU via __launch_bounds__(256,4); LDS 16.9KB -> 9/CU by LDS).
__global__ __launch_bounds__(256, 4) void fused_k(const float* __restrict__ in,
                                                  const int* __restrict__ neigh,
                                                  const float* __restrict__ w,
                                                  const float* __restrict__ gamma,
                                                  const float* __restrict__ beta,
                                                  float* __restrict__ y,     // out [32][N]
                                                  unsigned short* __restrict__ xTb,
                                                  unsigned short* __restrict__ wTb,
                                                  float* __restrict__ tot,   // [32][64] striped
                                                  int* __restrict__ bar,     // 4 ints, pre-zeroed
                                                  int N) {
    __shared__ float lds[4 * 32 * 33];   // reused: prep tile / conv ct[4] / stats sums

    const int tid   = threadIdx.x;
    const int nxblk = (N + 31) / 32;

    // ===== Phase P: prep (grid-stride over nxblk x-tiles + KK weight taps) =====
    {
        float (*tile)[33] = reinterpret_cast<float(*)[33]>(lds);
        for (int b = blockIdx.x; b < nxblk + KK; b += (int)gridDim.x) {
            if (b < nxblk) {
                int n0 = b * 32;
                int tx = tid & 31;
                int ty = tid >> 5;  // 0..7
                __syncthreads();    // protect tile across grid-stride iterations
#pragma unroll
                for (int c = ty; c < 32; c += 8) {
                    int n = n0 + tx;
                    tile[c][tx] = (n < N) ? in[(long)c * N + n] : 0.f;
                }
                __syncthreads();
#pragma unroll
                for (int nn = ty; nn < 32; nn += 8) {
                    int n = n0 + nn;
                    if (n < N) xTb[(long)n * 32 + tx] = f2bf(tile[tx][nn]);
                }
                if (b == 0 && tid < 32) xTb[(long)N * 32 + tid] = 0;  // zero row
            } else {
                int k = b - nxblk;
                for (int i = tid; i < 1024; i += 256) {
                    int cin = i >> 5, cout = i & 31;
                    wTb[k * 1024 + cout * 32 + cin] = f2bf(w[k * 1024 + cin * 32 + cout]);
                }
                if (k == 0) {
                    for (int i = tid; i < 32 * 64; i += 256) tot[i] = 0.f;
                }
            }
        }
    }
    grid_barrier(bar + 0, bar + 1);

    // ===== Phase C: conv (R0 inner loop; one wave per 32-node tile) =====
    {
        float (*ct)[32][33] = reinterpret_cast<float(*)[32][33]>(lds);
        const int L    = tid & 63;
        const int wv   = tid >> 6;                 // 0..3 independent waves
        const int ntiles = (N + 31) / 32;
        for (int tile_id = blockIdx.x * 4 + wv; tile_id < ntiles;
             tile_id += (int)gridDim.x * 4) {
            const int r16  = L & 15;
            const int quad = L >> 4;
            const int base = tile_id * 32;
            const int n0 = base + r16;
            const int n1 = base + 16 + r16;
            const bool v0 = (n0 < N), v1 = (n1 < N);
            const long nb0 = (long)(v0 ? n0 : 0) * KK;
            const long nb1 = (long)(v1 ? n1 : 0) * KK;

            f32x4 acc00 = {0.f, 0.f, 0.f, 0.f};
            f32x4 acc01 = acc00, acc10 = acc00, acc11 = acc00;

            int ia = v0 ? neigh[nb0] : N;
            int ib = v1 ? neigh[nb1] : N;
            int ja = v0 ? neigh[nb0 + 1] : N;
            int jb = v1 ? neigh[nb1 + 1] : N;

            bf16x8 a0 = *(const bf16x8*)(xTb + (long)ia * 32 + quad * 8);
            bf16x8 a1 = *(const bf16x8*)(xTb + (long)ib * 32 + quad * 8);
            bf16x8 b0 = *(const bf16x8*)(wTb + r16 * 32 + quad * 8);
            bf16x8 b1 = *(const bf16x8*)(wTb + (16 + r16) * 32 + quad * 8);

#pragma unroll 1
            for (int k = 0; k < KK; ++k) {
                bf16x8 na0, na1, pb0, pb1;
                if (k < KK - 1) {
                    na0 = *(const bf16x8*)(xTb + (long)ja * 32 + quad * 8);
                    na1 = *(const bf16x8*)(xTb + (long)jb * 32 + quad * 8);
                    const unsigned short* wn = wTb + (k + 1) * 1024;
                    pb0 = *(const bf16x8*)(wn + r16 * 32 + quad * 8);
                    pb1 = *(const bf16x8*)(wn + (16 + r16) * 32 + quad * 8);
                    int kk = (k + 2 < KK) ? (k + 2) : (KK - 1);
                    ja = v0 ? neigh[nb0 + kk] : N;
                    jb = v1 ? neigh[nb1 + kk] : N;
                }

                acc00 = __builtin_amdgcn_mfma_f32_16x16x32_bf16(a0, b0, acc00, 0, 0, 0);
                acc01 = __builtin_amdgcn_mfma_f32_16x16x32_bf16(a0, b1, acc01, 0, 0, 0);
                acc10 = __builtin_amdgcn_mfma_f32_16x16x32_bf16(a1, b0, acc10, 0, 0, 0);
                acc11 = __builtin_amdgcn_mfma_f32_16x16x32_bf16(a1, b1, acc11, 0, 0, 0);

                if (k < KK - 1) {
                    a0 = na0;
                    a1 = na1;
                    b0 = pb0;
                    b1 = pb1;
                }
            }

            // BN partials (sum over this wave's 32 nodes), striped atomics
            float s0 = 0.f, q0 = 0.f, s1 = 0.f, q1 = 0.f;
#pragma unroll
            for (int r = 0; r < 4; ++r) {
                s0 += acc00[r] + acc10[r];
                q0 += acc00[r] * acc00[r] + acc10[r] * acc10[r];
                s1 += acc01[r] + acc11[r];
                q1 += acc01[r] * acc01[r] + acc11[r] * acc11[r];
            }
#pragma unroll
            for (int off = 16; off < 64; off <<= 1) {
                s0 += __shfl_xor(s0, off, 64);
                q0 += __shfl_xor(q0, off, 64);
                s1 += __shfl_xor(s1, off, 64);
                q1 += __shfl_xor(q1, off, 64);
            }
            const int stripe = tile_id & 31;
            if (L < 16) {
                float* tb = tot + stripe * 64;
                atomicAdd(&tb[L],      s0);
                atomicAdd(&tb[L + 16], s1);
                atomicAdd(&tb[L + 32], q0);
                atomicAdd(&tb[L + 48], q1);
            }

            // per-wave LDS transpose -> coalesced y stores (wave-private slice)
#pragma unroll
            for (int r = 0; r < 4; ++r) {
                ct[wv][quad * 4 + r][r16]           = acc00[r];
                ct[wv][quad * 4 + r][16 + r16]      = acc01[r];
                ct[wv][16 + quad * 4 + r][r16]      = acc10[r];
                ct[wv][16 + quad * 4 + r][16 + r16] = acc11[r];
            }
            const int node = L & 31;
            const int half = L >> 5;
            const int gn = base + node;
            if (gn < N) {
#pragma unroll
                for (int i = 0; i < 16; ++i) {
                    const int cout = i * 2 + half;
                    y[(long)cout * N + gn] = ct[wv][node][cout];
                }
            }
        }
    }
    grid_barrier(bar + 2, bar + 3);

    // ===== Phase S: stripe-reduce BN sums into LDS (per block, 8KB L2-hot) =====
    if (tid < 64) {
        float v = 0.f;
#pragma unroll
        for (int s = 0; s < 32; ++s) v += tot[s * 64 + tid];
        lds[tid] = v;   // [0..31] = sum per cout, [32..63] = sumsq per cout
    }
    __syncthreads();

    // ===== Phase N: normalize y in place (grid-stride, d-major for coalescing) =====
    {
        const long N4 = ((long)N + 3) >> 2;
        const long items = 32 * N4;
        const float invN = 1.f / (float)N;
        for (long it = (long)blockIdx.x * 256 + tid; it < items;
             it += (long)gridDim.x * 256) {
            const int  d  = (int)(it / N4);
            const long i4 = it - (long)d * N4;
            const float mean = lds[d] * invN;
            const float var  = lds[32 + d] * invN - mean * mean;
            const float sc   = gamma[d] * rsqrtf(var + 1e-3f);
            const float sh   = beta[d] - mean * sc;
            const long base = i4 * 4;
            float* yp = y + (long)d * N + base;
            if (base + 3 < N) {
                float4 v = *(float4*)yp;
                v.x = fmaf(v.x, sc, sh);
                v.y = fmaf(v.y, sc, sh);
                v.z = fmaf(v.z, sc, sh);
                v.w = fmaf(v.w, sc, sh);
                *(float4*)yp = v;
            } else if (base < N) {
                for (long t = base; t < N; ++t)
                    y[(long)d * N + t] = fmaf(y[(long)d * N + t], sc, sh);
            }
        }
    }
}

// ---- launcher: memset barrier state + ONE regular launch (graph-capture safe) ----
extern "C" void kernel_launch(void* const* d_in, const int* in_sizes, int n_in,
                              void* d_out, int out_size, void* d_ws, size_t ws_size,
                              hipStream_t stream) {
    const float* data_in = (const float*)d_in[0];
    const int*   neigh   = (const int*)d_in[1];
    const float* weight  = (const float*)d_in[2];
    const float* gamma   = (const float*)d_in[3];
    const float* beta    = (const float*)d_in[4];
    float* out = (float*)d_out;

    int N = in_sizes[1] / KK;
    const int ntiles = (N + 31) / 32;
    int nblk = (ntiles + 3) / 4;        // exactly the conv need (782 @ N=100k)
    if (nblk > 1024) nblk = 1024;       // never exceed guaranteed-resident capacity
    if (nblk < 1) nblk = 1;

    char* ws = (char*)d_ws;
    unsigned short* xTb = (unsigned short*)ws;                            // (N+1)*32 bf16
    unsigned short* wTb = (unsigned short*)(ws + (size_t)(N + 1) * 64);   // 27*1024 bf16
    float* tot = (float*)(ws + (size_t)(N + 1) * 64 + 55296);             // 32*64 floats
    int*   bar = (int*)(tot + 32 * 64);                                   // 4 ints

    hipMemsetAsync(bar, 0, 4 * sizeof(int), stream);
    fused_k<<<dim3(nblk), dim3(256), 0, stream>>>(data_in, neigh, weight, gamma, beta,
                                                  out, xTb, wTb, tot, bar, N);
}